// Round 4
// baseline (135.380 us; speedup 1.0000x reference)
//
#include <hip/hip_runtime.h>
#include <hip/hip_bf16.h>
#include <cstdint>
#include <cstddef>

// out = (A2 @ E^T) @ W^T, A2[i,j] = a[i-j] lower-tri Toeplitz,
//   a[d] = (d/4096 + 1e-8)^0.2, a[0] = 1e-8^0.2
// gemm_a: T[i,e] = sum_{j<=i} a[i-j] * E[e,j]  (tri, split-j -> T0 + T1)
// gemm_b: out[i,v] = sum_e (T0+T1)[i,e] * W[v,e]
// Round 4: 128x128 blocks, 64x64 wave tiles (4x4 MFMA) -> LDS/MFMA pipes
// balanced at 0.5 b128-reads per MFMA; split-j for triangular load balance.

#define L_SER 4096
#define DEMB  1024
#define DV    1024

#define R_STRIDE 4224   // covers x up to 4223 (g = -64 case); 16B-aligned
#define R_O0     4096
#define LDP      72     // padded LDS row (elems): uniform bank groups on b128

typedef __bf16 bf16_t;
typedef __attribute__((ext_vector_type(8))) __bf16 bf16x8;
typedef __attribute__((ext_vector_type(4))) float f32x4;

// ---------------------------------------------------------------------------
__global__ void build_r_kernel(bf16_t* __restrict__ R) {
    int idx = blockIdx.x * blockDim.x + threadIdx.x;
    if (idx >= 8 * R_STRIDE) return;
    int s = idx / R_STRIDE;
    int x = idx - s * R_STRIDE;
    int d = R_O0 + s - x;
    float v = 0.0f;
    if (d >= 0 && d < L_SER)
        v = powf((d == 0) ? 1e-8f : ((float)d * (1.0f / (float)L_SER) + 1e-8f), 0.2f);
    R[idx] = (bf16_t)v;
}

__global__ void convert_kernel(const float* __restrict__ src, bf16_t* __restrict__ dst, int n8) {
    int idx = blockIdx.x * blockDim.x + threadIdx.x;
    if (idx >= n8) return;
    const f32x4* s = (const f32x4*)src;
    f32x4 v0 = s[idx * 2], v1 = s[idx * 2 + 1];
    bf16x8 o;
    o[0] = (bf16_t)v0[0]; o[1] = (bf16_t)v0[1]; o[2] = (bf16_t)v0[2]; o[3] = (bf16_t)v0[3];
    o[4] = (bf16_t)v1[0]; o[5] = (bf16_t)v1[1]; o[6] = (bf16_t)v1[2]; o[7] = (bf16_t)v1[3];
    ((bf16x8*)dst)[idx] = o;
}

// ---------------------------------------------------------------------------
// gemm_a: BM=128, BN=128, BK=64. 512 blocks: tile (I,n) x half h; each half
// has exactly I+1 K-steps. bid mapping pairs I with 31-I on a CU (sum 33).
// ---------------------------------------------------------------------------
__global__ __launch_bounds__(256) void gemm_a_kernel(const bf16_t* __restrict__ R,
                                                     const bf16_t* __restrict__ Eb,
                                                     bf16_t* __restrict__ T0,
                                                     bf16_t* __restrict__ T1) {
    __shared__ __align__(16) bf16_t sA[2][128 * LDP];   // 36 KB
    __shared__ __align__(16) bf16_t sB[2][128 * LDP];   // 36 KB

    const int bid = blockIdx.x;
    int I, nb, h;
    if (bid < 256) { I = bid >> 3;            nb = bid & 7;        h = 0; }
    else           { I = 31 - ((bid - 256) >> 3); nb = (bid - 256) & 7; h = 1; }
    const int i0 = I * 128;
    const int n0 = nb * 128;
    const int nsteps = I + 1;
    const int j0b = h ? 64 * (I + 1) : 0;
    bf16_t* __restrict__ Tout = h ? T1 : T0;

    const int tid  = threadIdx.x;
    const int wave = tid >> 6;
    const int lane = tid & 63;
    const int quad = lane >> 4;
    const int ln   = lane & 15;
    const int wm   = wave >> 1;
    const int wn   = wave & 1;
    const int srow = tid >> 3;              // 0..31
    const int kc8  = (tid & 7) * 8;

    f32x4 acc[4][4];
#pragma unroll
    for (int a = 0; a < 4; ++a)
#pragma unroll
        for (int b = 0; b < 4; ++b) acc[a][b] = (f32x4){0, 0, 0, 0};

    // Prefetch pointers. A row r: replica s=r&7, back-off 8*(r>>3):
    //   elem (r, col) at step j0 = R[s][R_O0 - (i0-j0) - 8*(r>>3) + col]
    const bf16_t* pA[4];
    const bf16_t* pB[4];
    bf16x8 ra[4], rb[4];
#pragma unroll
    for (int c = 0; c < 4; ++c) {
        int r = c * 32 + srow;
        pA[c] = R + (size_t)(r & 7) * R_STRIDE + (R_O0 - i0 + j0b - 8 * (r >> 3) + kc8);
        pB[c] = Eb + (size_t)(n0 + c * 32 + srow) * L_SER + j0b + kc8;
        ra[c] = *(const bf16x8*)pA[c];
        rb[c] = *(const bf16x8*)pB[c];
        pA[c] += 64; pB[c] += 64;
    }

    for (int step = 0; step < nsteps; ++step) {
        const int buf = step & 1;
#pragma unroll
        for (int c = 0; c < 4; ++c) {
            *(bf16x8*)&sA[buf][(c * 32 + srow) * LDP + kc8] = ra[c];
            *(bf16x8*)&sB[buf][(c * 32 + srow) * LDP + kc8] = rb[c];
        }
        __syncthreads();

        if (step + 1 < nsteps) {
#pragma unroll
            for (int c = 0; c < 4; ++c) {
                ra[c] = *(const bf16x8*)pA[c];
                rb[c] = *(const bf16x8*)pB[c];
                pA[c] += 64; pB[c] += 64;
            }
        }

#pragma unroll
        for (int kk = 0; kk < 2; ++kk) {
            bf16x8 afr[4], bfr[4];
#pragma unroll
            for (int tm = 0; tm < 4; ++tm)
                afr[tm] = *(const bf16x8*)&sA[buf][(wm * 64 + tm * 16 + ln) * LDP + kk * 32 + quad * 8];
#pragma unroll
            for (int tn = 0; tn < 4; ++tn)
                bfr[tn] = *(const bf16x8*)&sB[buf][(wn * 64 + tn * 16 + ln) * LDP + kk * 32 + quad * 8];
#pragma unroll
            for (int tm = 0; tm < 4; ++tm)
#pragma unroll
                for (int tn = 0; tn < 4; ++tn)
                    acc[tm][tn] = __builtin_amdgcn_mfma_f32_16x16x32_bf16(afr[tm], bfr[tn], acc[tm][tn], 0, 0, 0);
        }
    }

    // C/D: col = ln, row = quad*4 + r (m89-verified)
#pragma unroll
    for (int tm = 0; tm < 4; ++tm) {
        int row_base = i0 + wm * 64 + tm * 16 + quad * 4;
#pragma unroll
        for (int tn = 0; tn < 4; ++tn) {
            int col = n0 + wn * 64 + tn * 16 + ln;
#pragma unroll
            for (int r = 0; r < 4; ++r)
                Tout[(size_t)(row_base + r) * DEMB + col] = (bf16_t)acc[tm][tn][r];
        }
    }
}

// ---------------------------------------------------------------------------
// gemm_b: out[i,v] = sum_e (T0+T1)[i,e] * W[v,e]. BM=BN=128, BK=64, K=1024.
// ---------------------------------------------------------------------------
__global__ __launch_bounds__(256) void gemm_b_kernel(const bf16_t* __restrict__ T0,
                                                     const bf16_t* __restrict__ T1,
                                                     const bf16_t* __restrict__ Wb,
                                                     float* __restrict__ out) {
    __shared__ __align__(16) bf16_t sA[2][128 * LDP];
    __shared__ __align__(16) bf16_t sB[2][128 * LDP];

    const int i0 = blockIdx.y * 128;
    const int n0 = blockIdx.x * 128;

    const int tid  = threadIdx.x;
    const int wave = tid >> 6;
    const int lane = tid & 63;
    const int quad = lane >> 4;
    const int ln   = lane & 15;
    const int wm   = wave >> 1;
    const int wn   = wave & 1;
    const int srow = tid >> 3;
    const int kc8  = (tid & 7) * 8;

    f32x4 acc[4][4];
#pragma unroll
    for (int a = 0; a < 4; ++a)
#pragma unroll
        for (int b = 0; b < 4; ++b) acc[a][b] = (f32x4){0, 0, 0, 0};

    const int nsteps = DEMB / 64;   // 16

    const bf16_t* p0[4];
    const bf16_t* p1[4];
    const bf16_t* pW[4];
    bf16x8 ra[4], rb[4];
#pragma unroll
    for (int c = 0; c < 4; ++c) {
        size_t arow = (size_t)(i0 + c * 32 + srow) * DEMB + kc8;
        p0[c] = T0 + arow;
        p1[c] = T1 + arow;
        pW[c] = Wb + (size_t)(n0 + c * 32 + srow) * DEMB + kc8;
        ra[c] = *(const bf16x8*)p0[c] + *(const bf16x8*)p1[c];
        rb[c] = *(const bf16x8*)pW[c];
        p0[c] += 64; p1[c] += 64; pW[c] += 64;
    }

    for (int step = 0; step < nsteps; ++step) {
        const int buf = step & 1;
#pragma unroll
        for (int c = 0; c < 4; ++c) {
            *(bf16x8*)&sA[buf][(c * 32 + srow) * LDP + kc8] = ra[c];
            *(bf16x8*)&sB[buf][(c * 32 + srow) * LDP + kc8] = rb[c];
        }
        __syncthreads();

        if (step + 1 < nsteps) {
#pragma unroll
            for (int c = 0; c < 4; ++c) {
                ra[c] = *(const bf16x8*)p0[c] + *(const bf16x8*)p1[c];
                rb[c] = *(const bf16x8*)pW[c];
                p0[c] += 64; p1[c] += 64; pW[c] += 64;
            }
        }

#pragma unroll
        for (int kk = 0; kk < 2; ++kk) {
            bf16x8 afr[4], bfr[4];
#pragma unroll
            for (int tm = 0; tm < 4; ++tm)
                afr[tm] = *(const bf16x8*)&sA[buf][(wm * 64 + tm * 16 + ln) * LDP + kk * 32 + quad * 8];
#pragma unroll
            for (int tn = 0; tn < 4; ++tn)
                bfr[tn] = *(const bf16x8*)&sB[buf][(wn * 64 + tn * 16 + ln) * LDP + kk * 32 + quad * 8];
#pragma unroll
            for (int tm = 0; tm < 4; ++tm)
#pragma unroll
                for (int tn = 0; tn < 4; ++tn)
                    acc[tm][tn] = __builtin_amdgcn_mfma_f32_16x16x32_bf16(afr[tm], bfr[tn], acc[tm][tn], 0, 0, 0);
        }
    }

#pragma unroll
    for (int tm = 0; tm < 4; ++tm) {
        int row_base = i0 + wm * 64 + tm * 16 + quad * 4;
#pragma unroll
        for (int tn = 0; tn < 4; ++tn) {
            int col = n0 + wn * 64 + tn * 16 + ln;
#pragma unroll
            for (int r = 0; r < 4; ++r)
                out[(size_t)(row_base + r) * DV + col] = acc[tm][tn][r];
        }
    }
}

// ---------------------------------------------------------------------------
extern "C" void kernel_launch(void* const* d_in, const int* in_sizes, int n_in,
                              void* d_out, int out_size, void* d_ws, size_t ws_size,
                              hipStream_t stream) {
    const float* E = (const float*)d_in[0];   // (1024, 4096) f32
    const float* W = (const float*)d_in[1];   // (1024, 1024) f32
    float* out = (float*)d_out;               // (4096, 1024) f32

    char* ws = (char*)d_ws;
    bf16_t* Eb = (bf16_t*)(ws);                               // 8 MB
    bf16_t* T0 = (bf16_t*)(ws + (size_t)8  * 1024 * 1024);    // 8 MB
    bf16_t* T1 = (bf16_t*)(ws + (size_t)16 * 1024 * 1024);    // 8 MB
    bf16_t* Wb = (bf16_t*)(ws + (size_t)24 * 1024 * 1024);    // 2 MB
    bf16_t* R  = (bf16_t*)(ws + (size_t)26 * 1024 * 1024);    // 66 KB

    build_r_kernel<<<(8 * R_STRIDE + 255) / 256, 256, 0, stream>>>(R);
    convert_kernel<<<(DEMB * L_SER / 8 + 255) / 256, 256, 0, stream>>>(E, Eb, DEMB * L_SER / 8);
    convert_kernel<<<(DV * DEMB / 8 + 255) / 256, 256, 0, stream>>>(W, Wb, DV * DEMB / 8);

    gemm_a_kernel<<<512, 256, 0, stream>>>(R, Eb, T0, T1);
    gemm_b_kernel<<<dim3(DV / 128, L_SER / 128), 256, 0, stream>>>(T0, T1, Wb, out);
}